// Round 1
// baseline (803.137 us; speedup 1.0000x reference)
//
#include <hip/hip_runtime.h>
#include <math.h>

#define NNODES 100000
#define NEDGES 1600000
#define DIM 64
#define NGRAPHS 64
#define NEG_SLOPE 0.2f
#define SCAN_B 512
#define SCAN_NB ((NNODES + SCAN_B - 1) / SCAN_B)

// ---------------- CSR construction (dst-sorted), self-loops excluded ----------------

__global__ void zero_kernel(int* __restrict__ counts, float* __restrict__ pooled) {
    int i = blockIdx.x * blockDim.x + threadIdx.x;
    if (i <= NNODES) counts[i] = 0;
    if (i < NGRAPHS * DIM) pooled[i] = 0.f;
}

__global__ void hist_kernel(const int* __restrict__ src, const int* __restrict__ dst,
                            int* __restrict__ counts) {
    int e = blockIdx.x * blockDim.x + threadIdx.x;
    if (e < NEDGES) {
        int s = src[e], d = dst[e];
        if (s != d) atomicAdd(&counts[d], 1);  // src==dst originals are inert (masked -inf)
    }
}

// In-place exclusive scan of counts -> per-block, plus block sums
__global__ void scan1_kernel(int* __restrict__ data, int* __restrict__ bsum) {
    __shared__ int tmp[SCAN_B];
    int t = threadIdx.x;
    int i = blockIdx.x * SCAN_B + t;
    int v = (i < NNODES) ? data[i] : 0;
    tmp[t] = v;
    __syncthreads();
    for (int off = 1; off < SCAN_B; off <<= 1) {
        int a = (t >= off) ? tmp[t - off] : 0;
        __syncthreads();
        if (t >= off) tmp[t] += a;
        __syncthreads();
    }
    if (i < NNODES) data[i] = tmp[t] - v;          // exclusive within block
    if (t == SCAN_B - 1) bsum[blockIdx.x] = tmp[t]; // block total
}

__global__ void scan2_kernel(int* __restrict__ bsum, int* __restrict__ total) {
    if (threadIdx.x == 0 && blockIdx.x == 0) {
        int acc = 0;
        for (int b = 0; b < SCAN_NB; ++b) { int v = bsum[b]; bsum[b] = acc; acc += v; }
        *total = acc;
    }
}

__global__ void scan3_kernel(int* __restrict__ offs, const int* __restrict__ bsum,
                             const int* __restrict__ total, int* __restrict__ cursors) {
    int i = blockIdx.x * SCAN_B + threadIdx.x;
    if (i < NNODES) {
        int o = offs[i] + bsum[blockIdx.x];
        offs[i] = o;
        cursors[i] = o;
    }
    if (i == 0) offs[NNODES] = *total;
}

__global__ void scatter_kernel(const int* __restrict__ src, const int* __restrict__ dst,
                               const float* __restrict__ eattr, int* __restrict__ cursors,
                               int* __restrict__ csr_src, float* __restrict__ csr_val) {
    int e = blockIdx.x * blockDim.x + threadIdx.x;
    if (e < NEDGES) {
        int s = src[e], d = dst[e];
        if (s != d) {
            int p = atomicAdd(&cursors[d], 1);
            csr_src[p] = s;
            csr_val[p] = eattr[e];
        }
    }
}

// ---------------- h2 = hin @ W; alpha_d = h2.att[:64]; alpha_s = h2.att[64:128] ----------------
// 256 threads = 4 waves; block handles 16 rows (4 per wave). Wave lane = output column.
__global__ __launch_bounds__(256) void mm_alpha_kernel(
        const float* __restrict__ hin, const float* __restrict__ W, const float* __restrict__ att,
        float* __restrict__ h2, float* __restrict__ ad, float* __restrict__ as_) {
    __shared__ float wl[DIM * DIM];
    __shared__ float hrow[256];
    int t = threadIdx.x;
    for (int k = t; k < DIM * DIM; k += 256) wl[k] = W[k];
    __syncthreads();
    int lane = t & 63, w = t >> 6;
    float a0 = att[lane], a1 = att[DIM + lane];
    int rbase = blockIdx.x * 16 + w * 4;
    for (int r = 0; r < 4; ++r) {
        int i = rbase + r;
        float hv = hin[(size_t)i * DIM + lane];
        hrow[t] = hv;                       // same-wave LDS RAW: ordered, no barrier needed
        float acc = 0.f;
        #pragma unroll
        for (int k = 0; k < DIM; ++k)
            acc = fmaf(hrow[(w << 6) + k], wl[k * DIM + lane], acc);
        h2[(size_t)i * DIM + lane] = acc;
        float vd = acc * a0, vs = acc * a1;
        #pragma unroll
        for (int off = 32; off; off >>= 1) {
            vd += __shfl_xor(vd, off, 64);
            vs += __shfl_xor(vs, off, 64);
        }
        if (lane == 0) { ad[i] = vd; as_[i] = vs; }
    }
}

// ---------------- Per-node GAT aggregation: softmax over in-edges + weighted sum ----------------
// One wave per node; lane = channel. Self-loop handled inline (edge_attr = 0).
__global__ __launch_bounds__(256) void gat_agg_kernel(
        const float* __restrict__ h2, const float* __restrict__ ad, const float* __restrict__ as_,
        const int* __restrict__ offs, const int* __restrict__ csr_src, const float* __restrict__ csr_val,
        const float* __restrict__ att, const float* __restrict__ bias, float* __restrict__ hout) {
    int t = threadIdx.x, lane = t & 63, w = t >> 6;
    int i = blockIdx.x * 4 + w;
    float att2 = att[2 * DIM];
    int beg = offs[i], end = offs[i + 1];
    float adi = ad[i];
    // self-loop logit (edge feature 0)
    float ls = adi + as_[i];
    ls = ls >= 0.f ? ls : NEG_SLOPE * ls;
    // pass 1: segment max, lane-parallel over edges
    float m = ls;
    for (int e = beg + lane; e < end; e += 64) {
        float l = adi + as_[csr_src[e]] + csr_val[e] * att2;
        l = l >= 0.f ? l : NEG_SLOPE * l;
        m = fmaxf(m, l);
    }
    #pragma unroll
    for (int off = 32; off; off >>= 1) m = fmaxf(m, __shfl_xor(m, off, 64));
    // pass 2: exp lane-parallel in batches of 64, broadcast weights, accumulate channels
    float wself = expf(ls - m);
    float dsum = (lane == 0) ? wself : 0.f;
    float acc = wself * h2[(size_t)i * DIM + lane];
    for (int e0 = beg; e0 < end; e0 += 64) {
        int e = e0 + lane;
        float l = -INFINITY;
        int s = 0;
        if (e < end) {
            s = csr_src[e];
            l = adi + as_[s] + csr_val[e] * att2;
            l = l >= 0.f ? l : NEG_SLOPE * l;
        }
        float we = expf(l - m);   // inactive lanes: exp(-inf) = 0
        dsum += we;
        int cnt = min(64, end - e0);
        for (int j = 0; j < cnt; ++j) {
            float wgt = __shfl(we, j, 64);
            int sj = __shfl(s, j, 64);
            acc = fmaf(wgt, h2[(size_t)sj * DIM + lane], acc);
        }
    }
    #pragma unroll
    for (int off = 32; off; off >>= 1) dsum += __shfl_xor(dsum, off, 64);
    float o = acc / dsum + bias[lane];
    hout[(size_t)i * DIM + lane] = fmaxf(o, 0.f);
}

// ---------------- global_add_pool (batch is sorted) + final linear ----------------

__global__ __launch_bounds__(256) void pool_kernel(const float* __restrict__ h,
                                                   const int* __restrict__ batch,
                                                   float* __restrict__ pooled) {
    int t = threadIdx.x, lane = t & 63, w = t >> 6;
    int chunk = blockIdx.x * 4 + w;
    int i0 = chunk * 64;
    if (i0 >= NNODES) return;
    int iend = min(NNODES, i0 + 64);
    int cur = batch[i0];
    float acc = 0.f;
    for (int i = i0; i < iend; ++i) {
        int g = batch[i];                  // sorted: few transitions per chunk
        if (g != cur) { atomicAdd(&pooled[cur * DIM + lane], acc); acc = 0.f; cur = g; }
        acc += h[(size_t)i * DIM + lane];
    }
    atomicAdd(&pooled[cur * DIM + lane], acc);
}

__global__ void final_kernel(const float* __restrict__ pooled, const float* __restrict__ Wf,
                             const float* __restrict__ bf, float* __restrict__ out) {
    int t = threadIdx.x, lane = t & 63, w = t >> 6;
    for (int g = w; g < NGRAPHS; g += 4) {
        float v = pooled[g * DIM + lane] * Wf[lane];
        #pragma unroll
        for (int off = 32; off; off >>= 1) v += __shfl_xor(v, off, 64);
        if (lane == 0) out[g] = v + bf[0];
    }
}

// ---------------- launch ----------------

extern "C" void kernel_launch(void* const* d_in, const int* in_sizes, int n_in,
                              void* d_out, int out_size, void* d_ws, size_t ws_size,
                              hipStream_t stream) {
    const float* x      = (const float*)d_in[0];
    const int*   ei     = (const int*)d_in[1];
    const float* eattr  = (const float*)d_in[2];
    const int*   batch  = (const int*)d_in[3];
    const float* W[3]   = {(const float*)d_in[4], (const float*)d_in[7], (const float*)d_in[10]};
    const float* att[3] = {(const float*)d_in[5], (const float*)d_in[8], (const float*)d_in[11]};
    const float* bia[3] = {(const float*)d_in[6], (const float*)d_in[9], (const float*)d_in[12]};
    const float* Wf = (const float*)d_in[13];
    const float* bf = (const float*)d_in[14];
    float* out = (float*)d_out;
    const int* srcp = ei;            // edge_index row 0
    const int* dstp = ei + NEDGES;   // edge_index row 1

    char* p = (char*)d_ws;
    auto alloc = [&](size_t bytes) { char* r = p; p += (bytes + 255) & ~size_t(255); return r; };
    int*   offs    = (int*)alloc((NNODES + 1) * sizeof(int));
    int*   cursors = (int*)alloc(NNODES * sizeof(int));
    int*   bsum    = (int*)alloc(SCAN_NB * sizeof(int));
    int*   total   = (int*)alloc(sizeof(int));
    int*   csr_src = (int*)alloc((size_t)NEDGES * sizeof(int));
    float* csr_val = (float*)alloc((size_t)NEDGES * sizeof(float));
    float* h2      = (float*)alloc((size_t)NNODES * DIM * sizeof(float));
    float* ad      = (float*)alloc(NNODES * sizeof(float));
    float* as_     = (float*)alloc(NNODES * sizeof(float));
    float* hbuf    = (float*)alloc((size_t)NNODES * DIM * sizeof(float));
    float* pooled  = (float*)alloc(NGRAPHS * DIM * sizeof(float));

    // CSR build (same work every call; edges are layer-invariant)
    zero_kernel<<<(NNODES + 256) / 256, 256, 0, stream>>>(offs, pooled);
    hist_kernel<<<(NEDGES + 255) / 256, 256, 0, stream>>>(srcp, dstp, offs);
    scan1_kernel<<<SCAN_NB, SCAN_B, 0, stream>>>(offs, bsum);
    scan2_kernel<<<1, 64, 0, stream>>>(bsum, total);
    scan3_kernel<<<SCAN_NB, SCAN_B, 0, stream>>>(offs, bsum, total, cursors);
    scatter_kernel<<<(NEDGES + 255) / 256, 256, 0, stream>>>(srcp, dstp, eattr, cursors,
                                                             csr_src, csr_val);

    // 3 GAT layers (ping: matmul writes h2, aggregate writes hbuf which is next input)
    const float* hin = x;
    for (int l = 0; l < 3; ++l) {
        mm_alpha_kernel<<<NNODES / 16, 256, 0, stream>>>(hin, W[l], att[l], h2, ad, as_);
        gat_agg_kernel<<<NNODES / 4, 256, 0, stream>>>(h2, ad, as_, offs, csr_src, csr_val,
                                                       att[l], bia[l], hbuf);
        hin = hbuf;
    }

    pool_kernel<<<(((NNODES + 63) / 64) + 3) / 4, 256, 0, stream>>>(hbuf, batch, pooled);
    final_kernel<<<1, 256, 0, stream>>>(pooled, Wf, bf, out);
}